// Round 13
// baseline (312.772 us; speedup 1.0000x reference)
//
#include <hip/hip_runtime.h>

#define NN 50000
#define MPAD 50048          // 391 tiles * 128
#define NE 800000
#define SCAN_BLOCKS 49      // ceil(50000 / 1024)

typedef short short8 __attribute__((ext_vector_type(8)));
typedef float f32x4 __attribute__((ext_vector_type(4)));

__device__ __forceinline__ unsigned short f2bf(float x) {
    unsigned u = __builtin_bit_cast(unsigned, x);
    u += 0x7FFFu + ((u >> 16) & 1u);          // RNE
    return (unsigned short)(u >> 16);
}
__device__ __forceinline__ float bf2f(unsigned short h) {
    unsigned u = ((unsigned)h) << 16;
    return __builtin_bit_cast(float, u);
}
__device__ __forceinline__ void gld16(const void* g, void* l) {
    __builtin_amdgcn_global_load_lds(
        (const __attribute__((address_space(1))) unsigned int*)g,
        (__attribute__((address_space(3))) unsigned int*)l, 16, 0, 0);
}
__device__ __forceinline__ void nt_store8(void* p, ushort4 v) {
    __builtin_nontemporal_store(__builtin_bit_cast(unsigned long long, v),
                                (unsigned long long*)p);
}
__device__ __forceinline__ int nt_load_i(const int* p) {
    return __builtin_nontemporal_load(p);
}

// ---------- CSR build: count + fused splitW ----------
// Blocks 0..39 additionally transpose/split W1,W2 (independent of counting).
__global__ __launch_bounds__(256) void count_kernel(const int* __restrict__ src,
    const int* __restrict__ dst, int* __restrict__ cnt_out, int* __restrict__ cnt_in,
    const float* __restrict__ W1, const float* __restrict__ W2,
    unsigned short* __restrict__ W1T, unsigned short* __restrict__ W2T, int E)
{
    int e = blockIdx.x * 256 + threadIdx.x;
    if (e < E) {
        atomicAdd(&cnt_out[src[e]], 1);
        atomicAdd(&cnt_in[dst[e]], 1);
    }
    int i = blockIdx.x * 256 + threadIdx.x;      // splitW item = col*32 + kc
    if (i < 320 * 32) {
        const float* W; unsigned short* BT; int N; int ii;
        if (i < 256 * 32) { W = W1; BT = W1T; N = 256; ii = i; }
        else { W = W2; BT = W2T; N = 64; ii = i - 256 * 32; }
        int col = ii >> 5, kc = ii & 31;
        short8 hv, lv;
        #pragma unroll
        for (int j = 0; j < 8; ++j) {
            float x = W[(size_t)(kc * 8 + j) * N + col];
            unsigned short h = f2bf(x);
            hv[j] = (short)h;
            lv[j] = (short)f2bf(x - bf2f(h));
        }
        size_t base = (size_t)col * 512;
        size_t o = (kc >> 3) * 64 + (((kc & 7) ^ (col & 7)) * 8);
        *(short8*)&BT[base + o] = hv;
        *(short8*)&BT[base + 256 + o] = lv;
    }
}

// Single-pass exclusive scan of cnt_in -> rs with chained lookback (49 blocks,
// all co-resident -> deadlock-free). Also computes inv_in/inv_out.
__global__ __launch_bounds__(256) void scan_kernel(const int* __restrict__ cnt_in,
    const int* __restrict__ cnt_out, int* __restrict__ bsum, int* __restrict__ rs,
    float* __restrict__ inv_out, float* __restrict__ inv_in)
{
    __shared__ int sm[4];
    __shared__ int sprefix;
    const int b = blockIdx.x, tid = threadIdx.x;
    const int lane = tid & 63, wv = tid >> 6;
    int base = b * 1024 + tid * 4;
    int v[4]; int s = 0;
    #pragma unroll
    for (int i = 0; i < 4; ++i) {
        int idx = base + i;
        v[i] = (idx < NN) ? cnt_in[idx] : 0;
        s += v[i];
    }
    int inc = s;
    #pragma unroll
    for (int off = 1; off < 64; off <<= 1) {
        int u = __shfl_up(inc, off, 64);
        if (lane >= off) inc += u;
    }
    if (lane == 63) sm[wv] = inc;
    __syncthreads();
    if (tid == 0) {
        int btot = sm[0] + sm[1] + sm[2] + sm[3];
        atomicExch(&bsum[b], btot + 1);
    }
    if (tid < 64) {
        int pv = 0;
        if (lane < b) {
            int x;
            do { x = atomicAdd(&bsum[lane], 0); } while (x == 0);
            pv = x - 1;
        }
        #pragma unroll
        for (int off = 1; off < 64; off <<= 1) pv += __shfl_xor(pv, off, 64);
        if (lane == 0) sprefix = pv;
    }
    __syncthreads();
    int wo = 0;
    for (int i = 0; i < wv; ++i) wo += sm[i];
    int run = sprefix + wo + (inc - s);
    #pragma unroll
    for (int i = 0; i < 4; ++i) {
        int idx = base + i;
        if (idx < NN) {
            rs[idx] = run; run += v[i];
            inv_in[idx]  = rsqrtf(fmaxf((float)v[i], 1.0f));
            inv_out[idx] = rsqrtf(fmaxf((float)cnt_out[idx], 1.0f));
        }
    }
}

__global__ __launch_bounds__(256) void fill_kernel(const int* __restrict__ src,
    const int* __restrict__ dst, int* __restrict__ rs, int* __restrict__ csr_src, int E)
{
    int e = blockIdx.x * 256 + threadIdx.x;
    if (e < E) {
        int slot = atomicAdd(&rs[dst[e]], 1);
        csr_src[slot] = src[e];
    }
}

// ---------- GEMM1: fused split — A read fp32 from X, converted in-regs ----------
__global__ __launch_bounds__(256) void gemm1_fuse_kernel(const float* __restrict__ X,
    const unsigned short* __restrict__ BT, const float* __restrict__ inv_out,
    unsigned short* __restrict__ C, int M)
{
    constexpr int BN = 128, WN = 64, NF = 4;
    __shared__ unsigned short Ash[128 * 64];
    __shared__ unsigned short Asl[128 * 64];
    __shared__ unsigned short Bsh[BN * 64];
    __shared__ unsigned short Bsl[BN * 64];
    const int tid = threadIdx.x;
    const int w = tid >> 6, lane = tid & 63;
    const int wm = w >> 1, wn = w & 1;
    const int r = lane & 15, kg = lane >> 4;
    const int rowbase = blockIdx.x * 128;
    const int colbase = blockIdx.y * BN;

    f32x4 acc[4][NF] = {};

    for (int kb = 0; kb < 4; ++kb) {
        #pragma unroll
        for (int i = 0; i < 4; ++i) {
            int ct = (w * 4 + i) * 64 + lane;
            int row = ct >> 3, c = ct & 7;
            int grow = rowbase + row; if (grow >= NN) grow = NN - 1;
            const float* sp = X + (size_t)grow * 256 + kb * 64 + c * 8;
            float4 x0 = *(const float4*)sp;
            float4 x1 = *(const float4*)(sp + 4);
            float xs[8] = {x0.x, x0.y, x0.z, x0.w, x1.x, x1.y, x1.z, x1.w};
            short8 hv, lv;
            #pragma unroll
            for (int t = 0; t < 8; ++t) {
                unsigned short h = f2bf(xs[t]);
                hv[t] = (short)h;
                lv[t] = (short)f2bf(xs[t] - bf2f(h));
            }
            int dsto = row * 64 + ((c ^ (row & 7)) * 8);
            *(short8*)&Ash[dsto] = hv;
            *(short8*)&Asl[dsto] = lv;
        }
        #pragma unroll
        for (int i = 0; i < 4; ++i) {
            int ct = (w * 4 + i) * 64 + lane;
            int col = ct >> 3, c = ct & 7;
            size_t goff = (size_t)(colbase + col) * 512 + kb * 64 + c * 8;
            gld16(BT + goff, (unsigned short*)Bsh + (size_t)ct * 8);
            gld16(BT + goff + 256, (unsigned short*)Bsl + (size_t)ct * 8);
        }
        __syncthreads();
        #pragma unroll
        for (int ks = 0; ks < 2; ++ks) {
            short8 ahf[4], alf[4];
            #pragma unroll
            for (int mf = 0; mf < 4; ++mf) {
                int row = wm * 64 + mf * 16 + r;
                int lo = row * 64 + (((ks * 4 + kg) ^ (row & 7)) * 8);
                ahf[mf] = *(const short8*)&Ash[lo];
                alf[mf] = *(const short8*)&Asl[lo];
            }
            #pragma unroll
            for (int nf = 0; nf < NF; ++nf) {
                int col = wn * WN + nf * 16 + r;
                int lo = col * 64 + (((ks * 4 + kg) ^ (col & 7)) * 8);
                short8 bh = *(const short8*)&Bsh[lo];
                short8 bl = *(const short8*)&Bsl[lo];
                #pragma unroll
                for (int mf = 0; mf < 4; ++mf) {
                    acc[mf][nf] = __builtin_amdgcn_mfma_f32_16x16x32_bf16(ahf[mf], bh, acc[mf][nf], 0, 0, 0);
                    acc[mf][nf] = __builtin_amdgcn_mfma_f32_16x16x32_bf16(alf[mf], bh, acc[mf][nf], 0, 0, 0);
                    acc[mf][nf] = __builtin_amdgcn_mfma_f32_16x16x32_bf16(ahf[mf], bl, acc[mf][nf], 0, 0, 0);
                }
            }
        }
        __syncthreads();
    }

    #pragma unroll
    for (int mf = 0; mf < 4; ++mf) {
        #pragma unroll
        for (int reg = 0; reg < 4; ++reg) {
            int orow = rowbase + wm * 64 + mf * 16 + kg * 4 + reg;
            if (orow >= M) continue;
            float sc = inv_out[orow];
            #pragma unroll
            for (int nf = 0; nf < NF; ++nf) {
                int ocol = colbase + wn * WN + nf * 16 + r;
                C[(size_t)orow * 256 + ocol] = f2bf(acc[mf][nf][reg] * sc);
            }
        }
    }
}

// ---------- GEMM2: A via gld16 from swizzled Ah2/Al2 images, B via gld16 ----------
__global__ __launch_bounds__(256) void gemm2_kernel(
    const unsigned short* __restrict__ Ah, const unsigned short* __restrict__ Al,
    const unsigned short* __restrict__ BT, const float* __restrict__ inv_out,
    unsigned short* __restrict__ C, int M)
{
    constexpr int BN = 64, WN = 32, NF = 2, BI = 2;
    __shared__ unsigned short Ash[128 * 64];
    __shared__ unsigned short Asl[128 * 64];
    __shared__ unsigned short Bsh[BN * 64];
    __shared__ unsigned short Bsl[BN * 64];
    const int tid = threadIdx.x;
    const int w = tid >> 6, lane = tid & 63;
    const int wm = w >> 1, wn = w & 1;
    const int r = lane & 15, kg = lane >> 4;
    const int rowbase = blockIdx.x * 128;

    f32x4 acc[4][NF] = {};

    for (int kb = 0; kb < 4; ++kb) {
        #pragma unroll
        for (int i = 0; i < 4; ++i) {
            int ct = (w * 4 + i) * 64 + lane;
            int row = ct >> 3, c = ct & 7;
            size_t goff = (size_t)(rowbase + row) * 256 + kb * 64 + c * 8;
            gld16(Ah + goff, (unsigned short*)Ash + (size_t)ct * 8);
            gld16(Al + goff, (unsigned short*)Asl + (size_t)ct * 8);
        }
        #pragma unroll
        for (int i = 0; i < BI; ++i) {
            int ct = (w * BI + i) * 64 + lane;
            int col = ct >> 3, c = ct & 7;
            size_t goff = (size_t)col * 512 + kb * 64 + c * 8;
            gld16(BT + goff, (unsigned short*)Bsh + (size_t)ct * 8);
            gld16(BT + goff + 256, (unsigned short*)Bsl + (size_t)ct * 8);
        }
        __syncthreads();
        #pragma unroll
        for (int ks = 0; ks < 2; ++ks) {
            short8 ahf[4], alf[4];
            #pragma unroll
            for (int mf = 0; mf < 4; ++mf) {
                int row = wm * 64 + mf * 16 + r;
                int lo = row * 64 + (((ks * 4 + kg) ^ (row & 7)) * 8);
                ahf[mf] = *(const short8*)&Ash[lo];
                alf[mf] = *(const short8*)&Asl[lo];
            }
            #pragma unroll
            for (int nf = 0; nf < NF; ++nf) {
                int col = wn * WN + nf * 16 + r;
                int lo = col * 64 + (((ks * 4 + kg) ^ (col & 7)) * 8);
                short8 bh = *(const short8*)&Bsh[lo];
                short8 bl = *(const short8*)&Bsl[lo];
                #pragma unroll
                for (int mf = 0; mf < 4; ++mf) {
                    acc[mf][nf] = __builtin_amdgcn_mfma_f32_16x16x32_bf16(ahf[mf], bh, acc[mf][nf], 0, 0, 0);
                    acc[mf][nf] = __builtin_amdgcn_mfma_f32_16x16x32_bf16(alf[mf], bh, acc[mf][nf], 0, 0, 0);
                    acc[mf][nf] = __builtin_amdgcn_mfma_f32_16x16x32_bf16(ahf[mf], bl, acc[mf][nf], 0, 0, 0);
                }
            }
        }
        __syncthreads();
    }

    #pragma unroll
    for (int mf = 0; mf < 4; ++mf) {
        #pragma unroll
        for (int reg = 0; reg < 4; ++reg) {
            int orow = rowbase + wm * 64 + mf * 16 + kg * 4 + reg;
            if (orow >= M) continue;
            float sc = inv_out[orow];
            #pragma unroll
            for (int nf = 0; nf < NF; ++nf) {
                int ocol = wn * WN + nf * 16 + r;
                C[(size_t)orow * 64 + ocol] = f2bf(acc[mf][nf][reg] * sc);
            }
        }
    }
}

// ---------- gather 256-wide over node range [n0, n1) ----------
__global__ __launch_bounds__(256) void gather256_kernel(const unsigned short* __restrict__ t1,
    const int* __restrict__ csr_src, const int* __restrict__ rs,
    const float* __restrict__ inv_in, const float* __restrict__ b1,
    unsigned short* __restrict__ Ah2, unsigned short* __restrict__ Al2, int n0, int n1)
{
    int n = n0 + (int)((blockIdx.x * 256 + threadIdx.x) >> 6);
    int lane = threadIdx.x & 63;
    if (n >= n1) return;
    int begin = (n == 0) ? 0 : rs[n - 1];
    int end = rs[n];
    float a0 = 0.f, a1 = 0.f, a2 = 0.f, a3 = 0.f;
    int j = begin;
    for (; j + 8 <= end; j += 8) {
        int s0 = nt_load_i(csr_src + j),     s1 = nt_load_i(csr_src + j + 1);
        int s2 = nt_load_i(csr_src + j + 2), s3 = nt_load_i(csr_src + j + 3);
        int s4 = nt_load_i(csr_src + j + 4), s5 = nt_load_i(csr_src + j + 5);
        int s6 = nt_load_i(csr_src + j + 6), s7 = nt_load_i(csr_src + j + 7);
        ushort4 v0 = *(const ushort4*)&t1[(size_t)s0 * 256 + lane * 4];
        ushort4 v1 = *(const ushort4*)&t1[(size_t)s1 * 256 + lane * 4];
        ushort4 v2 = *(const ushort4*)&t1[(size_t)s2 * 256 + lane * 4];
        ushort4 v3 = *(const ushort4*)&t1[(size_t)s3 * 256 + lane * 4];
        ushort4 v4 = *(const ushort4*)&t1[(size_t)s4 * 256 + lane * 4];
        ushort4 v5 = *(const ushort4*)&t1[(size_t)s5 * 256 + lane * 4];
        ushort4 v6 = *(const ushort4*)&t1[(size_t)s6 * 256 + lane * 4];
        ushort4 v7 = *(const ushort4*)&t1[(size_t)s7 * 256 + lane * 4];
        a0 += bf2f(v0.x); a1 += bf2f(v0.y); a2 += bf2f(v0.z); a3 += bf2f(v0.w);
        a0 += bf2f(v1.x); a1 += bf2f(v1.y); a2 += bf2f(v1.z); a3 += bf2f(v1.w);
        a0 += bf2f(v2.x); a1 += bf2f(v2.y); a2 += bf2f(v2.z); a3 += bf2f(v2.w);
        a0 += bf2f(v3.x); a1 += bf2f(v3.y); a2 += bf2f(v3.z); a3 += bf2f(v3.w);
        a0 += bf2f(v4.x); a1 += bf2f(v4.y); a2 += bf2f(v4.z); a3 += bf2f(v4.w);
        a0 += bf2f(v5.x); a1 += bf2f(v5.y); a2 += bf2f(v5.z); a3 += bf2f(v5.w);
        a0 += bf2f(v6.x); a1 += bf2f(v6.y); a2 += bf2f(v6.z); a3 += bf2f(v6.w);
        a0 += bf2f(v7.x); a1 += bf2f(v7.y); a2 += bf2f(v7.z); a3 += bf2f(v7.w);
    }
    for (; j < end; ++j) {
        int s = csr_src[j];
        ushort4 v = *(const ushort4*)&t1[(size_t)s * 256 + lane * 4];
        a0 += bf2f(v.x); a1 += bf2f(v.y); a2 += bf2f(v.z); a3 += bf2f(v.w);
    }
    float win = inv_in[n];
    int f0 = lane * 4;
    float4 bb = *(const float4*)&b1[f0];
    float x0 = fmaxf(fmaf(a0, win, bb.x), 0.f);
    float x1 = fmaxf(fmaf(a1, win, bb.y), 0.f);
    float x2 = fmaxf(fmaf(a2, win, bb.z), 0.f);
    float x3 = fmaxf(fmaf(a3, win, bb.w), 0.f);
    unsigned short h0 = f2bf(x0), h1 = f2bf(x1), h2 = f2bf(x2), h3 = f2bf(x3);
    ushort4 hv = {h0, h1, h2, h3};
    ushort4 lv = {f2bf(x0 - bf2f(h0)), f2bf(x1 - bf2f(h1)),
                  f2bf(x2 - bf2f(h2)), f2bf(x3 - bf2f(h3))};
    int kb = f0 >> 6, c = (f0 >> 3) & 7, e = f0 & 7;
    size_t off = (size_t)n * 256 + kb * 64 + ((c ^ (n & 7)) * 8) + e;
    nt_store8(&Ah2[off], hv);
    nt_store8(&Al2[off], lv);
}

// ---------- gather 64-wide: wave/node, lane owns one bf16, unroll-8, +b2 ----------
__global__ __launch_bounds__(256) void gather64_kernel(const unsigned short* __restrict__ t2,
    const int* __restrict__ csr_src, const int* __restrict__ rs,
    const float* __restrict__ inv_in, const float* __restrict__ b2,
    float* __restrict__ out)
{
    int n = (int)((blockIdx.x * 256 + threadIdx.x) >> 6);
    int lane = threadIdx.x & 63;
    if (n >= NN) return;
    int begin = (n == 0) ? 0 : rs[n - 1];
    int end = rs[n];
    float acc = 0.f;
    int j = begin;
    for (; j + 8 <= end; j += 8) {
        int s0 = nt_load_i(csr_src + j),     s1 = nt_load_i(csr_src + j + 1);
        int s2 = nt_load_i(csr_src + j + 2), s3 = nt_load_i(csr_src + j + 3);
        int s4 = nt_load_i(csr_src + j + 4), s5 = nt_load_i(csr_src + j + 5);
        int s6 = nt_load_i(csr_src + j + 6), s7 = nt_load_i(csr_src + j + 7);
        float v0 = bf2f(t2[(size_t)s0 * 64 + lane]);
        float v1 = bf2f(t2[(size_t)s1 * 64 + lane]);
        float v2 = bf2f(t2[(size_t)s2 * 64 + lane]);
        float v3 = bf2f(t2[(size_t)s3 * 64 + lane]);
        float v4 = bf2f(t2[(size_t)s4 * 64 + lane]);
        float v5 = bf2f(t2[(size_t)s5 * 64 + lane]);
        float v6 = bf2f(t2[(size_t)s6 * 64 + lane]);
        float v7 = bf2f(t2[(size_t)s7 * 64 + lane]);
        acc += v0; acc += v1; acc += v2; acc += v3;
        acc += v4; acc += v5; acc += v6; acc += v7;
    }
    for (; j < end; ++j) {
        int s = csr_src[j];
        acc += bf2f(t2[(size_t)s * 64 + lane]);
    }
    float o = fmaf(acc, inv_in[n], b2[lane]);
    __builtin_nontemporal_store(o, &out[(size_t)n * 64 + lane]);
}

extern "C" void kernel_launch(void* const* d_in, const int* in_sizes, int n_in,
                              void* d_out, int out_size, void* d_ws, size_t ws_size,
                              hipStream_t stream)
{
    const float* features = (const float*)d_in[0];
    const int*   edge_index = (const int*)d_in[1];
    const float* W1 = (const float*)d_in[2];
    const float* b1 = (const float*)d_in[3];
    const float* W2 = (const float*)d_in[4];
    const float* b2 = (const float*)d_in[5];
    float* out = (float*)d_out;
    const int* src = edge_index;
    const int* dst = edge_index + NE;

    char* p = (char*)d_ws;
    int* cnt_out = (int*)p;            p += (size_t)NN * 4;
    int* cnt_in  = (int*)p;            p += (size_t)NN * 4;   // contiguous after cnt_out
    int* bsum    = (int*)p;            p += 64 * 4;           // one memset covers all 3
    float* inv_out = (float*)p;        p += (size_t)NN * 4;
    float* inv_in  = (float*)p;        p += (size_t)NN * 4;
    int* rs      = (int*)p;            p += (size_t)NN * 4;
    int* csr_src = (int*)p;            p += (size_t)NE * 4;
    unsigned short* W1T = (unsigned short*)p;  p += (size_t)256 * 512 * 2;
    unsigned short* W2T = (unsigned short*)p;  p += (size_t)64 * 512 * 2;
    unsigned short* t1  = (unsigned short*)p;  p += (size_t)NN * 256 * 2;
    unsigned short* Ah2 = (unsigned short*)p;  p += (size_t)MPAD * 256 * 2;
    unsigned short* Al2 = (unsigned short*)p;  p += (size_t)MPAD * 256 * 2;
    unsigned short* t2  = (unsigned short*)p;  p += (size_t)NN * 64 * 2;

    hipMemsetAsync(cnt_out, 0, (2 * (size_t)NN + 64) * sizeof(int), stream);

    count_kernel<<<(NE + 255) / 256, 256, 0, stream>>>(
        src, dst, cnt_out, cnt_in, W1, W2, W1T, W2T, NE);
    scan_kernel<<<SCAN_BLOCKS, 256, 0, stream>>>(cnt_in, cnt_out, bsum, rs, inv_out, inv_in);
    fill_kernel<<<(NE + 255) / 256, 256, 0, stream>>>(src, dst, rs, csr_src, NE);

    // t1(bf16, linear) = (X @ W1) * inv_out[row]  — split fused in-kernel
    gemm1_fuse_kernel<<<dim3(MPAD / 128, 2), 256, 0, stream>>>(
        features, W1T, inv_out, t1, NN);

    // Ah2/Al2(swz) = split(relu(sum_{e:dst=n} t1[src] * inv_in[n] + b1)) — 3 node slices
    const int NS = 16672;   // ceil(50000/3) rounded to multiple of 4
    for (int s0 = 0; s0 < NN; s0 += NS) {
        int s1 = s0 + NS < NN ? s0 + NS : NN;
        int nodes = s1 - s0;
        gather256_kernel<<<(nodes * 64 + 255) / 256, 256, 0, stream>>>(
            t1, csr_src, rs, inv_in, b1, Ah2, Al2, s0, s1);
    }

    // t2(bf16, linear) = (h2 @ W2) * inv_out[row]
    gemm2_kernel<<<MPAD / 128, 256, 0, stream>>>(
        Ah2, Al2, W2T, inv_out, t2, NN);

    // out = sum t2[src] * inv_in[n] + b2
    gather64_kernel<<<(NN * 64 + 255) / 256, 256, 0, stream>>>(
        t2, csr_src, rs, inv_in, b2, out);
}

// Round 14
// 296.543 us; speedup vs baseline: 1.0547x; 1.0547x over previous
//
#include <hip/hip_runtime.h>

#define NN 50000
#define MPAD 50048          // 391 tiles * 128
#define NE 800000
#define SCAN_BLOCKS 49      // ceil(50000 / 1024)

typedef short short8 __attribute__((ext_vector_type(8)));
typedef float f32x4 __attribute__((ext_vector_type(4)));

__device__ __forceinline__ unsigned short f2bf(float x) {
    unsigned u = __builtin_bit_cast(unsigned, x);
    u += 0x7FFFu + ((u >> 16) & 1u);          // RNE
    return (unsigned short)(u >> 16);
}
__device__ __forceinline__ float bf2f(unsigned short h) {
    unsigned u = ((unsigned)h) << 16;
    return __builtin_bit_cast(float, u);
}
__device__ __forceinline__ void gld16(const void* g, void* l) {
    __builtin_amdgcn_global_load_lds(
        (const __attribute__((address_space(1))) unsigned int*)g,
        (__attribute__((address_space(3))) unsigned int*)l, 16, 0, 0);
}
__device__ __forceinline__ void nt_store8(void* p, ushort4 v) {
    __builtin_nontemporal_store(__builtin_bit_cast(unsigned long long, v),
                                (unsigned long long*)p);
}
__device__ __forceinline__ unsigned xcc_id() {
    unsigned x;
    asm("s_getreg_b32 %0, hwreg(HW_REG_XCC_ID)" : "=s"(x));
    return x & 7;
}

// ---------- CSR build: per-XCD privatized count + fused splitW ----------
// cntp layout: [xcd][0..NN) = out-degree, [xcd][NN..2NN) = in-degree.
// Atomics are XCD-local (workgroup scope -> execute in local L2, no
// memory-side write-through). Correct because copy x is only ever touched
// by waves physically on XCD x.
__global__ __launch_bounds__(256) void count_kernel(const int* __restrict__ src,
    const int* __restrict__ dst, int* __restrict__ cntp,
    const float* __restrict__ W1, const float* __restrict__ W2,
    unsigned short* __restrict__ W1T, unsigned short* __restrict__ W2T, int E)
{
    int* mycnt = cntp + (size_t)xcc_id() * (2 * NN);
    int e = blockIdx.x * 256 + threadIdx.x;
    if (e < E) {
        int s = src[e], d = dst[e];
        __hip_atomic_fetch_add(&mycnt[s], 1, __ATOMIC_RELAXED, __HIP_MEMORY_SCOPE_WORKGROUP);
        __hip_atomic_fetch_add(&mycnt[NN + d], 1, __ATOMIC_RELAXED, __HIP_MEMORY_SCOPE_WORKGROUP);
    }
    int i = blockIdx.x * 256 + threadIdx.x;      // splitW item = col*32 + kc
    if (i < 320 * 32) {
        const float* W; unsigned short* BT; int N; int ii;
        if (i < 256 * 32) { W = W1; BT = W1T; N = 256; ii = i; }
        else { W = W2; BT = W2T; N = 64; ii = i - 256 * 32; }
        int col = ii >> 5, kc = ii & 31;
        short8 hv, lv;
        #pragma unroll
        for (int j = 0; j < 8; ++j) {
            float x = W[(size_t)(kc * 8 + j) * N + col];
            unsigned short h = f2bf(x);
            hv[j] = (short)h;
            lv[j] = (short)f2bf(x - bf2f(h));
        }
        size_t base = (size_t)col * 512;
        size_t o = (kc >> 3) * 64 + (((kc & 7) ^ (col & 7)) * 8);
        *(short8*)&BT[base + o] = hv;
        *(short8*)&BT[base + 256 + o] = lv;
    }
}

// Single-pass exclusive scan over summed in-degrees -> rs (exclusive, rs[NN]=NE),
// chained lookback across 49 co-resident blocks. Emits inv_in/inv_out and the
// per-XCD fill sub-offsets rsp[x][n] = rs[n] + sum_{y<x} cnt_in_y[n].
__global__ __launch_bounds__(256) void scan_kernel(const int* __restrict__ cntp,
    int* __restrict__ bsum, int* __restrict__ rs, int* __restrict__ rsp,
    float* __restrict__ inv_out, float* __restrict__ inv_in)
{
    __shared__ int sm[4];
    __shared__ int sprefix;
    const int b = blockIdx.x, tid = threadIdx.x;
    const int lane = tid & 63, wv = tid >> 6;
    int base = b * 1024 + tid * 4;
    int v[4]; int s = 0;
    #pragma unroll
    for (int i = 0; i < 4; ++i) {
        int idx = base + i;
        int t = 0;
        if (idx < NN) {
            #pragma unroll
            for (int x = 0; x < 8; ++x)
                t += cntp[(size_t)x * (2 * NN) + NN + idx];
        }
        v[i] = t; s += t;
    }
    int inc = s;
    #pragma unroll
    for (int off = 1; off < 64; off <<= 1) {
        int u = __shfl_up(inc, off, 64);
        if (lane >= off) inc += u;
    }
    if (lane == 63) sm[wv] = inc;
    __syncthreads();
    if (tid == 0) {
        int btot = sm[0] + sm[1] + sm[2] + sm[3];
        atomicExch(&bsum[b], btot + 1);
    }
    if (tid < 64) {
        int pv = 0;
        if (lane < b) {
            int x;
            do { x = atomicAdd(&bsum[lane], 0); } while (x == 0);
            pv = x - 1;
        }
        #pragma unroll
        for (int off = 1; off < 64; off <<= 1) pv += __shfl_xor(pv, off, 64);
        if (lane == 0) sprefix = pv;
    }
    __syncthreads();
    int wo = 0;
    for (int i = 0; i < wv; ++i) wo += sm[i];
    int run = sprefix + wo + (inc - s);
    #pragma unroll
    for (int i = 0; i < 4; ++i) {
        int idx = base + i;
        if (idx < NN) {
            rs[idx] = run;
            int rx = run;
            #pragma unroll
            for (int x = 0; x < 8; ++x) {
                rsp[(size_t)x * NN + idx] = rx;
                rx += cntp[(size_t)x * (2 * NN) + NN + idx];
            }
            run += v[i];
            inv_in[idx] = rsqrtf(fmaxf((float)v[i], 1.0f));
            int dout = 0;
            #pragma unroll
            for (int x = 0; x < 8; ++x) dout += cntp[(size_t)x * (2 * NN) + idx];
            inv_out[idx] = rsqrtf(fmaxf((float)dout, 1.0f));
        }
    }
    if (b == 0 && tid == 0) rs[NN] = NE;
}

// Bucket fill with XCD-local slot allocation (each XCD owns a pre-reserved
// sub-range of every dst bucket).
__global__ __launch_bounds__(256) void fill_kernel(const int* __restrict__ src,
    const int* __restrict__ dst, int* __restrict__ rsp, int* __restrict__ csr_src, int E)
{
    int* myrs = rsp + (size_t)xcc_id() * NN;
    int e = blockIdx.x * 256 + threadIdx.x;
    if (e < E) {
        int slot = __hip_atomic_fetch_add(&myrs[dst[e]], 1, __ATOMIC_RELAXED,
                                          __HIP_MEMORY_SCOPE_WORKGROUP);
        csr_src[slot] = src[e];
    }
}

// ---------- GEMM1: fused split — A read fp32 from X, converted in-regs ----------
__global__ __launch_bounds__(256) void gemm1_fuse_kernel(const float* __restrict__ X,
    const unsigned short* __restrict__ BT, const float* __restrict__ inv_out,
    unsigned short* __restrict__ C, int M)
{
    constexpr int BN = 128, WN = 64, NF = 4;
    __shared__ unsigned short Ash[128 * 64];
    __shared__ unsigned short Asl[128 * 64];
    __shared__ unsigned short Bsh[BN * 64];
    __shared__ unsigned short Bsl[BN * 64];
    const int tid = threadIdx.x;
    const int w = tid >> 6, lane = tid & 63;
    const int wm = w >> 1, wn = w & 1;
    const int r = lane & 15, kg = lane >> 4;
    const int rowbase = blockIdx.x * 128;
    const int colbase = blockIdx.y * BN;

    f32x4 acc[4][NF] = {};

    for (int kb = 0; kb < 4; ++kb) {
        #pragma unroll
        for (int i = 0; i < 4; ++i) {
            int ct = (w * 4 + i) * 64 + lane;
            int row = ct >> 3, c = ct & 7;
            int grow = rowbase + row; if (grow >= NN) grow = NN - 1;
            const float* sp = X + (size_t)grow * 256 + kb * 64 + c * 8;
            float4 x0 = *(const float4*)sp;
            float4 x1 = *(const float4*)(sp + 4);
            float xs[8] = {x0.x, x0.y, x0.z, x0.w, x1.x, x1.y, x1.z, x1.w};
            short8 hv, lv;
            #pragma unroll
            for (int t = 0; t < 8; ++t) {
                unsigned short h = f2bf(xs[t]);
                hv[t] = (short)h;
                lv[t] = (short)f2bf(xs[t] - bf2f(h));
            }
            int dsto = row * 64 + ((c ^ (row & 7)) * 8);
            *(short8*)&Ash[dsto] = hv;
            *(short8*)&Asl[dsto] = lv;
        }
        #pragma unroll
        for (int i = 0; i < 4; ++i) {
            int ct = (w * 4 + i) * 64 + lane;
            int col = ct >> 3, c = ct & 7;
            size_t goff = (size_t)(colbase + col) * 512 + kb * 64 + c * 8;
            gld16(BT + goff, (unsigned short*)Bsh + (size_t)ct * 8);
            gld16(BT + goff + 256, (unsigned short*)Bsl + (size_t)ct * 8);
        }
        __syncthreads();
        #pragma unroll
        for (int ks = 0; ks < 2; ++ks) {
            short8 ahf[4], alf[4];
            #pragma unroll
            for (int mf = 0; mf < 4; ++mf) {
                int row = wm * 64 + mf * 16 + r;
                int lo = row * 64 + (((ks * 4 + kg) ^ (row & 7)) * 8);
                ahf[mf] = *(const short8*)&Ash[lo];
                alf[mf] = *(const short8*)&Asl[lo];
            }
            #pragma unroll
            for (int nf = 0; nf < NF; ++nf) {
                int col = wn * WN + nf * 16 + r;
                int lo = col * 64 + (((ks * 4 + kg) ^ (col & 7)) * 8);
                short8 bh = *(const short8*)&Bsh[lo];
                short8 bl = *(const short8*)&Bsl[lo];
                #pragma unroll
                for (int mf = 0; mf < 4; ++mf) {
                    acc[mf][nf] = __builtin_amdgcn_mfma_f32_16x16x32_bf16(ahf[mf], bh, acc[mf][nf], 0, 0, 0);
                    acc[mf][nf] = __builtin_amdgcn_mfma_f32_16x16x32_bf16(alf[mf], bh, acc[mf][nf], 0, 0, 0);
                    acc[mf][nf] = __builtin_amdgcn_mfma_f32_16x16x32_bf16(ahf[mf], bl, acc[mf][nf], 0, 0, 0);
                }
            }
        }
        __syncthreads();
    }

    #pragma unroll
    for (int mf = 0; mf < 4; ++mf) {
        #pragma unroll
        for (int reg = 0; reg < 4; ++reg) {
            int orow = rowbase + wm * 64 + mf * 16 + kg * 4 + reg;
            if (orow >= M) continue;
            float sc = inv_out[orow];
            #pragma unroll
            for (int nf = 0; nf < NF; ++nf) {
                int ocol = colbase + wn * WN + nf * 16 + r;
                C[(size_t)orow * 256 + ocol] = f2bf(acc[mf][nf][reg] * sc);
            }
        }
    }
}

// ---------- GEMM2: A via gld16 from swizzled Ah2/Al2 images, B via gld16 ----------
__global__ __launch_bounds__(256) void gemm2_kernel(
    const unsigned short* __restrict__ Ah, const unsigned short* __restrict__ Al,
    const unsigned short* __restrict__ BT, const float* __restrict__ inv_out,
    unsigned short* __restrict__ C, int M)
{
    constexpr int BN = 64, WN = 32, NF = 2, BI = 2;
    __shared__ unsigned short Ash[128 * 64];
    __shared__ unsigned short Asl[128 * 64];
    __shared__ unsigned short Bsh[BN * 64];
    __shared__ unsigned short Bsl[BN * 64];
    const int tid = threadIdx.x;
    const int w = tid >> 6, lane = tid & 63;
    const int wm = w >> 1, wn = w & 1;
    const int r = lane & 15, kg = lane >> 4;
    const int rowbase = blockIdx.x * 128;

    f32x4 acc[4][NF] = {};

    for (int kb = 0; kb < 4; ++kb) {
        #pragma unroll
        for (int i = 0; i < 4; ++i) {
            int ct = (w * 4 + i) * 64 + lane;
            int row = ct >> 3, c = ct & 7;
            size_t goff = (size_t)(rowbase + row) * 256 + kb * 64 + c * 8;
            gld16(Ah + goff, (unsigned short*)Ash + (size_t)ct * 8);
            gld16(Al + goff, (unsigned short*)Asl + (size_t)ct * 8);
        }
        #pragma unroll
        for (int i = 0; i < BI; ++i) {
            int ct = (w * BI + i) * 64 + lane;
            int col = ct >> 3, c = ct & 7;
            size_t goff = (size_t)col * 512 + kb * 64 + c * 8;
            gld16(BT + goff, (unsigned short*)Bsh + (size_t)ct * 8);
            gld16(BT + goff + 256, (unsigned short*)Bsl + (size_t)ct * 8);
        }
        __syncthreads();
        #pragma unroll
        for (int ks = 0; ks < 2; ++ks) {
            short8 ahf[4], alf[4];
            #pragma unroll
            for (int mf = 0; mf < 4; ++mf) {
                int row = wm * 64 + mf * 16 + r;
                int lo = row * 64 + (((ks * 4 + kg) ^ (row & 7)) * 8);
                ahf[mf] = *(const short8*)&Ash[lo];
                alf[mf] = *(const short8*)&Asl[lo];
            }
            #pragma unroll
            for (int nf = 0; nf < NF; ++nf) {
                int col = wn * WN + nf * 16 + r;
                int lo = col * 64 + (((ks * 4 + kg) ^ (col & 7)) * 8);
                short8 bh = *(const short8*)&Bsh[lo];
                short8 bl = *(const short8*)&Bsl[lo];
                #pragma unroll
                for (int mf = 0; mf < 4; ++mf) {
                    acc[mf][nf] = __builtin_amdgcn_mfma_f32_16x16x32_bf16(ahf[mf], bh, acc[mf][nf], 0, 0, 0);
                    acc[mf][nf] = __builtin_amdgcn_mfma_f32_16x16x32_bf16(alf[mf], bh, acc[mf][nf], 0, 0, 0);
                    acc[mf][nf] = __builtin_amdgcn_mfma_f32_16x16x32_bf16(ahf[mf], bl, acc[mf][nf], 0, 0, 0);
                }
            }
        }
        __syncthreads();
    }

    #pragma unroll
    for (int mf = 0; mf < 4; ++mf) {
        #pragma unroll
        for (int reg = 0; reg < 4; ++reg) {
            int orow = rowbase + wm * 64 + mf * 16 + kg * 4 + reg;
            if (orow >= M) continue;
            float sc = inv_out[orow];
            #pragma unroll
            for (int nf = 0; nf < NF; ++nf) {
                int ocol = wn * WN + nf * 16 + r;
                C[(size_t)orow * 64 + ocol] = f2bf(acc[mf][nf][reg] * sc);
            }
        }
    }
}

// ---------- gather 256-wide: wave/node, lane owns feature-quad, unroll-8 ----------
__global__ __launch_bounds__(256) void gather256_kernel(const unsigned short* __restrict__ t1,
    const int* __restrict__ csr_src, const int* __restrict__ rs,
    const float* __restrict__ inv_in, const float* __restrict__ b1,
    unsigned short* __restrict__ Ah2, unsigned short* __restrict__ Al2)
{
    int n = (int)((blockIdx.x * 256 + threadIdx.x) >> 6);
    int lane = threadIdx.x & 63;
    if (n >= NN) return;
    int begin = rs[n];
    int end = rs[n + 1];
    float a0 = 0.f, a1 = 0.f, a2 = 0.f, a3 = 0.f;
    int j = begin;
    for (; j + 8 <= end; j += 8) {
        int s0 = csr_src[j],     s1 = csr_src[j + 1], s2 = csr_src[j + 2], s3 = csr_src[j + 3];
        int s4 = csr_src[j + 4], s5 = csr_src[j + 5], s6 = csr_src[j + 6], s7 = csr_src[j + 7];
        ushort4 v0 = *(const ushort4*)&t1[(size_t)s0 * 256 + lane * 4];
        ushort4 v1 = *(const ushort4*)&t1[(size_t)s1 * 256 + lane * 4];
        ushort4 v2 = *(const ushort4*)&t1[(size_t)s2 * 256 + lane * 4];
        ushort4 v3 = *(const ushort4*)&t1[(size_t)s3 * 256 + lane * 4];
        ushort4 v4 = *(const ushort4*)&t1[(size_t)s4 * 256 + lane * 4];
        ushort4 v5 = *(const ushort4*)&t1[(size_t)s5 * 256 + lane * 4];
        ushort4 v6 = *(const ushort4*)&t1[(size_t)s6 * 256 + lane * 4];
        ushort4 v7 = *(const ushort4*)&t1[(size_t)s7 * 256 + lane * 4];
        a0 += bf2f(v0.x); a1 += bf2f(v0.y); a2 += bf2f(v0.z); a3 += bf2f(v0.w);
        a0 += bf2f(v1.x); a1 += bf2f(v1.y); a2 += bf2f(v1.z); a3 += bf2f(v1.w);
        a0 += bf2f(v2.x); a1 += bf2f(v2.y); a2 += bf2f(v2.z); a3 += bf2f(v2.w);
        a0 += bf2f(v3.x); a1 += bf2f(v3.y); a2 += bf2f(v3.z); a3 += bf2f(v3.w);
        a0 += bf2f(v4.x); a1 += bf2f(v4.y); a2 += bf2f(v4.z); a3 += bf2f(v4.w);
        a0 += bf2f(v5.x); a1 += bf2f(v5.y); a2 += bf2f(v5.z); a3 += bf2f(v5.w);
        a0 += bf2f(v6.x); a1 += bf2f(v6.y); a2 += bf2f(v6.z); a3 += bf2f(v6.w);
        a0 += bf2f(v7.x); a1 += bf2f(v7.y); a2 += bf2f(v7.z); a3 += bf2f(v7.w);
    }
    for (; j < end; ++j) {
        int s = csr_src[j];
        ushort4 v = *(const ushort4*)&t1[(size_t)s * 256 + lane * 4];
        a0 += bf2f(v.x); a1 += bf2f(v.y); a2 += bf2f(v.z); a3 += bf2f(v.w);
    }
    float win = inv_in[n];
    int f0 = lane * 4;
    float4 bb = *(const float4*)&b1[f0];
    float x0 = fmaxf(fmaf(a0, win, bb.x), 0.f);
    float x1 = fmaxf(fmaf(a1, win, bb.y), 0.f);
    float x2 = fmaxf(fmaf(a2, win, bb.z), 0.f);
    float x3 = fmaxf(fmaf(a3, win, bb.w), 0.f);
    unsigned short h0 = f2bf(x0), h1 = f2bf(x1), h2 = f2bf(x2), h3 = f2bf(x3);
    ushort4 hv = {h0, h1, h2, h3};
    ushort4 lv = {f2bf(x0 - bf2f(h0)), f2bf(x1 - bf2f(h1)),
                  f2bf(x2 - bf2f(h2)), f2bf(x3 - bf2f(h3))};
    int kb = f0 >> 6, c = (f0 >> 3) & 7, e = f0 & 7;
    size_t off = (size_t)n * 256 + kb * 64 + ((c ^ (n & 7)) * 8) + e;
    nt_store8(&Ah2[off], hv);
    nt_store8(&Al2[off], lv);
}

// ---------- gather 64-wide: wave/node, lane owns one bf16, unroll-8, +b2 ----------
__global__ __launch_bounds__(256) void gather64_kernel(const unsigned short* __restrict__ t2,
    const int* __restrict__ csr_src, const int* __restrict__ rs,
    const float* __restrict__ inv_in, const float* __restrict__ b2,
    float* __restrict__ out)
{
    int n = (int)((blockIdx.x * 256 + threadIdx.x) >> 6);
    int lane = threadIdx.x & 63;
    if (n >= NN) return;
    int begin = rs[n];
    int end = rs[n + 1];
    float acc = 0.f;
    int j = begin;
    for (; j + 8 <= end; j += 8) {
        int s0 = csr_src[j],     s1 = csr_src[j + 1], s2 = csr_src[j + 2], s3 = csr_src[j + 3];
        int s4 = csr_src[j + 4], s5 = csr_src[j + 5], s6 = csr_src[j + 6], s7 = csr_src[j + 7];
        float v0 = bf2f(t2[(size_t)s0 * 64 + lane]);
        float v1 = bf2f(t2[(size_t)s1 * 64 + lane]);
        float v2 = bf2f(t2[(size_t)s2 * 64 + lane]);
        float v3 = bf2f(t2[(size_t)s3 * 64 + lane]);
        float v4 = bf2f(t2[(size_t)s4 * 64 + lane]);
        float v5 = bf2f(t2[(size_t)s5 * 64 + lane]);
        float v6 = bf2f(t2[(size_t)s6 * 64 + lane]);
        float v7 = bf2f(t2[(size_t)s7 * 64 + lane]);
        acc += v0; acc += v1; acc += v2; acc += v3;
        acc += v4; acc += v5; acc += v6; acc += v7;
    }
    for (; j < end; ++j) {
        int s = csr_src[j];
        acc += bf2f(t2[(size_t)s * 64 + lane]);
    }
    float o = fmaf(acc, inv_in[n], b2[lane]);
    __builtin_nontemporal_store(o, &out[(size_t)n * 64 + lane]);
}

extern "C" void kernel_launch(void* const* d_in, const int* in_sizes, int n_in,
                              void* d_out, int out_size, void* d_ws, size_t ws_size,
                              hipStream_t stream)
{
    const float* features = (const float*)d_in[0];
    const int*   edge_index = (const int*)d_in[1];
    const float* W1 = (const float*)d_in[2];
    const float* b1 = (const float*)d_in[3];
    const float* W2 = (const float*)d_in[4];
    const float* b2 = (const float*)d_in[5];
    float* out = (float*)d_out;
    const int* src = edge_index;
    const int* dst = edge_index + NE;

    char* p = (char*)d_ws;
    int* cntp = (int*)p;               p += (size_t)8 * 2 * NN * 4;   // per-XCD histograms
    int* bsum = (int*)p;               p += 64 * 4;                   // zeroed with cntp
    int* rs   = (int*)p;               p += (size_t)(NN + 1) * 4;
    int* rsp  = (int*)p;               p += (size_t)8 * NN * 4;       // per-XCD fill cursors
    float* inv_out = (float*)p;        p += (size_t)NN * 4;
    float* inv_in  = (float*)p;        p += (size_t)NN * 4;
    int* csr_src = (int*)p;            p += (size_t)NE * 4;
    unsigned short* W1T = (unsigned short*)p;  p += (size_t)256 * 512 * 2;
    unsigned short* W2T = (unsigned short*)p;  p += (size_t)64 * 512 * 2;
    unsigned short* t1  = (unsigned short*)p;  p += (size_t)NN * 256 * 2;
    unsigned short* Ah2 = (unsigned short*)p;  p += (size_t)MPAD * 256 * 2;
    unsigned short* Al2 = (unsigned short*)p;  p += (size_t)MPAD * 256 * 2;
    unsigned short* t2  = (unsigned short*)p;  p += (size_t)NN * 64 * 2;

    hipMemsetAsync(cntp, 0, ((size_t)8 * 2 * NN + 64) * sizeof(int), stream);

    count_kernel<<<(NE + 255) / 256, 256, 0, stream>>>(
        src, dst, cntp, W1, W2, W1T, W2T, NE);
    scan_kernel<<<SCAN_BLOCKS, 256, 0, stream>>>(cntp, bsum, rs, rsp, inv_out, inv_in);
    fill_kernel<<<(NE + 255) / 256, 256, 0, stream>>>(src, dst, rsp, csr_src, NE);

    // t1(bf16, linear) = (X @ W1) * inv_out[row]  — split fused in-kernel
    gemm1_fuse_kernel<<<dim3(MPAD / 128, 2), 256, 0, stream>>>(
        features, W1T, inv_out, t1, NN);

    // Ah2/Al2(swz) = split(relu(sum_{e:dst=n} t1[src] * inv_in[n] + b1))
    gather256_kernel<<<(NN * 64 + 255) / 256, 256, 0, stream>>>(
        t1, csr_src, rs, inv_in, b1, Ah2, Al2);

    // t2(bf16, linear) = (h2 @ W2) * inv_out[row]
    gemm2_kernel<<<MPAD / 128, 256, 0, stream>>>(
        Ah2, Al2, W2T, inv_out, t2, NN);

    // out = sum t2[src] * inv_in[n] + b2
    gather64_kernel<<<(NN * 64 + 255) / 256, 256, 0, stream>>>(
        t2, csr_src, rs, inv_in, b2, out);
}